// Round 7
// baseline (1806.893 us; speedup 1.0000x reference)
//
#include <hip/hip_runtime.h>
#include <math.h>

#define N_TOK 2000
#define NH 8
#define HD 32
#define SCALE 25.0f
#define SIM_TH 0.75f
#define EPSF 1e-8f
#define GSLOT 16   // ceil(2000/128) slots per 128-thread group
#define GTAIL 80   // valid lanes in slot 15: 2000 - 15*128

// force a uniform value into an SGPR so dot-loop FMAs are v_fmac(v, s, v)
__device__ __forceinline__ float rfl(float x) {
  return __int_as_float(__builtin_amdgcn_readfirstlane(__float_as_int(x)));
}

// dot of two uniform q[32] (SGPR) against one K row; 4+4 load split (known
// spill-free shape from round 5 — DOT8 at 8-in-flight caused 256-VGPR spill).
#define DOT_BODY(kt4, mc, d0, d1)                                         \
  {                                                                       \
    float4 kv[4];                                                         \
    _Pragma("unroll") for (int g_ = 0; g_ < 4; g_++) kv[g_] =             \
        kt4[g_ * N_TOK + (mc)];                                           \
    _Pragma("unroll") for (int g_ = 0; g_ < 4; g_++) {                    \
      d0 += q0[4 * g_] * kv[g_].x + q0[4 * g_ + 1] * kv[g_].y +           \
            q0[4 * g_ + 2] * kv[g_].z + q0[4 * g_ + 3] * kv[g_].w;        \
      d1 += q1[4 * g_] * kv[g_].x + q1[4 * g_ + 1] * kv[g_].y +           \
            q1[4 * g_ + 2] * kv[g_].z + q1[4 * g_ + 3] * kv[g_].w;        \
    }                                                                     \
    _Pragma("unroll") for (int g_ = 0; g_ < 4; g_++) kv[g_] =             \
        kt4[(g_ + 4) * N_TOK + (mc)];                                     \
    _Pragma("unroll") for (int g_ = 0; g_ < 4; g_++) {                    \
      d0 += q0[4 * g_ + 16] * kv[g_].x + q0[4 * g_ + 17] * kv[g_].y +     \
            q0[4 * g_ + 18] * kv[g_].z + q0[4 * g_ + 19] * kv[g_].w;      \
      d1 += q1[4 * g_ + 16] * kv[g_].x + q1[4 * g_ + 17] * kv[g_].y +     \
            q1[4 * g_ + 18] * kv[g_].z + q1[4 * g_ + 19] * kv[g_].w;      \
    }                                                                     \
  }

// ---------------------------------------------------------------------------
// Kernel 1: QKV projection + l2norm (unchanged; ~70 us).
// grid = (500, 2), block = 256
// ---------------------------------------------------------------------------
__global__ __launch_bounds__(256) void qkv_norm_kernel(
    const float* __restrict__ x_cls, const float* __restrict__ x_reg,
    const float* __restrict__ W_cls, const float* __restrict__ W_reg,
    float* __restrict__ qn_cls, float* __restrict__ qn_reg,
    float* __restrict__ kct, float* __restrict__ krt,
    float* __restrict__ vnt, float* __restrict__ v_rm) {
  __shared__ float xs[4][256];
  __shared__ float res[4][768];
  __shared__ float inv_norm[96];

  const int n0 = blockIdx.x * 4;
  const int which = blockIdx.y;
  const int tid = threadIdx.x;
  const float* __restrict__ x = which ? x_reg : x_cls;
  const float* __restrict__ W = which ? W_reg : W_cls;

#pragma unroll
  for (int r = 0; r < 4; r++) xs[r][tid] = x[(n0 + r) * 256 + tid];
  __syncthreads();

  float acc[4][3];
#pragma unroll
  for (int r = 0; r < 4; r++) acc[r][0] = acc[r][1] = acc[r][2] = 0.f;

  for (int k = 0; k < 256; k++) {
    const float* __restrict__ wr = W + k * 768;
    const float w0 = wr[tid], w1 = wr[tid + 256], w2 = wr[tid + 512];
#pragma unroll
    for (int r = 0; r < 4; r++) {
      const float xv = xs[r][k];
      acc[r][0] += xv * w0;
      acc[r][1] += xv * w1;
      acc[r][2] += xv * w2;
    }
  }
#pragma unroll
  for (int r = 0; r < 4; r++) {
    res[r][tid] = acc[r][0];
    res[r][tid + 256] = acc[r][1];
    res[r][tid + 512] = acc[r][2];
  }
  __syncthreads();

  if (tid < 96) {
    const int r = tid / 24, grp = tid % 24;
    float ss = 0.f;
#pragma unroll
    for (int d = 0; d < HD; d++) {
      const float v = res[r][grp * 32 + d];
      ss += v * v;
    }
    inv_norm[tid] = 1.0f / (sqrtf(ss) + EPSF);
  }
  __syncthreads();

#pragma unroll
  for (int j = 0; j < 3; j++) {
    const int c = tid + j * 256;
    const int qkv = c >> 8, grp = c >> 5;
    const int h = grp & 7, d = c & 31;
    const int g = d >> 2, comp = d & 3;
#pragma unroll
    for (int r = 0; r < 4; r++) {
      const int n = n0 + r;
      const float val = res[r][c];
      const float nval = val * inv_norm[r * 24 + grp];
      if (qkv == 0) {
        (which ? qn_reg : qn_cls)[(h * N_TOK + n) * HD + d] = nval;
      } else if (qkv == 1) {
        (which ? krt : kct)[((h * 8 + g) * N_TOK + n) * 4 + comp] = nval;
      } else if (which == 0) {
        v_rm[(h * N_TOK + n) * HD + d] = val;
        vnt[((h * 8 + g) * N_TOK + n) * 4 + comp] = nval;
      }
    }
  }
}

// ---------------------------------------------------------------------------
// Kernel 2: 4 query rows per block via two 128-thread (2-wave) groups; each
// group owns a query PAIR (q in per-wave SGPRs). Both groups sweep the same
// m-chunks concurrently -> the 2nd group's K loads hit L1; L2 traffic /2 vs
// round 5. e_cls/e_reg live in LDS (fp32); only sim/raw accumulators stay in
// register slots (m = gt + 128*t). Fixed-shift softmax (score <= 25).
// LDS ~72KB -> 2 blocks/CU. grid = 500, block = 256.
// ---------------------------------------------------------------------------
__global__ __launch_bounds__(256) void attn7_kernel(
    const float* __restrict__ qn_cls, const float* __restrict__ qn_reg,
    const float* __restrict__ kct, const float* __restrict__ krt,
    const float* __restrict__ vnt, const float* __restrict__ v_rm,
    float* __restrict__ out_x, float* __restrict__ out_sim) {
  __shared__ float s_ec[4][N_TOK];   // 32 KB, rows = block-local query 0..3
  __shared__ float s_er[4][N_TOK];   // 32 KB
  __shared__ float4 part4[32][2][8]; // 8 KB (reused for both pairs)
  __shared__ float redm[2][2][4];    // [group][wave-in-group][4 sums]

  const int tid = threadIdx.x;
  const int g = tid >> 7;        // group 0/1
  const int gt = tid & 127;      // thread within group
  const int wig = (tid >> 6) & 1;  // wave within group
  const int i0 = blockIdx.x * 4;
  const int iA = i0 + 2 * g;
  const int iB = iA + 1;
  const int bs = (iA / 10) * 10;  // iA even -> iA,iB share the decade

  // per-thread accumulators over the group's slot space (m = gt + 128*t)
  float sim0[GSLOT], sim1[GSLOT], raw0[GSLOT], raw1[GSLOT];
#pragma unroll
  for (int t = 0; t < GSLOT; t++) {
    sim0[t] = 0.f; sim1[t] = 0.f; raw0[t] = 0.f; raw1[t] = 0.f;
  }

  float q0[HD], q1[HD];  // wave-uniform -> SGPRs (per-wave register files)

  for (int hh = 0; hh < NH; hh++) {
    const int h = (blockIdx.x + hh) & 7;  // XCD-local head schedule

    // ===== phase C: cls scores -> e = exp(25s-25) -> s_ec + running sum ===
    {
      const float* __restrict__ p0 = qn_cls + (size_t)(h * N_TOK + iA) * HD;
      const float* __restrict__ p1 = qn_cls + (size_t)(h * N_TOK + iB) * HD;
#pragma unroll
      for (int d = 0; d < HD; d++) { q0[d] = rfl(p0[d]); q1[d] = rfl(p1[d]); }
    }
    float ls0 = 0.f, ls1 = 0.f;
    {
      const float4* __restrict__ kt4 = (const float4*)kct + (size_t)h * 8 * N_TOK;
#pragma unroll
      for (int t = 0; t < GSLOT; t++) {
        const int m = gt + 128 * t;
        const bool valid = (t < 15) || (gt < GTAIL);
        const int mc = valid ? m : (N_TOK - 1);
        float d0 = 0.f, d1 = 0.f;
        DOT_BODY(kt4, mc, d0, d1);
        const float e0 = valid ? __expf(d0 * SCALE - SCALE) : 0.f;
        const float e1 = valid ? __expf(d1 * SCALE - SCALE) : 0.f;
        ls0 += e0; ls1 += e1;
        if (valid) {
          s_ec[2 * g][m] = e0;
          s_ec[2 * g + 1][m] = e1;
        }
      }
    }

    // ===== phase R: reg scores -> s_er + running sum =====
    {
      const float* __restrict__ p0 = qn_reg + (size_t)(h * N_TOK + iA) * HD;
      const float* __restrict__ p1 = qn_reg + (size_t)(h * N_TOK + iB) * HD;
#pragma unroll
      for (int d = 0; d < HD; d++) { q0[d] = rfl(p0[d]); q1[d] = rfl(p1[d]); }
    }
    float lr0 = 0.f, lr1 = 0.f;
    {
      const float4* __restrict__ kt4 = (const float4*)krt + (size_t)h * 8 * N_TOK;
#pragma unroll
      for (int t = 0; t < GSLOT; t++) {
        const int m = gt + 128 * t;
        const bool valid = (t < 15) || (gt < GTAIL);
        const int mc = valid ? m : (N_TOK - 1);
        float d0 = 0.f, d1 = 0.f;
        DOT_BODY(kt4, mc, d0, d1);
        const float e0 = valid ? __expf(d0 * SCALE - SCALE) : 0.f;
        const float e1 = valid ? __expf(d1 * SCALE - SCALE) : 0.f;
        lr0 += e0; lr1 += e1;
        if (valid) {
          s_er[2 * g][m] = e0;
          s_er[2 * g + 1][m] = e1;
        }
      }
    }

    // ===== phase V: vn cosine -> raw register slots =====
    {
#pragma unroll
      for (int d = 0; d < HD; d++) {
        const int gg = d >> 2, comp = d & 3;
        q0[d] = rfl(vnt[((size_t)(h * 8 + gg) * N_TOK + iA) * 4 + comp]);
        q1[d] = rfl(vnt[((size_t)(h * 8 + gg) * N_TOK + iB) * 4 + comp]);
      }
      const float4* __restrict__ kt4 = (const float4*)vnt + (size_t)h * 8 * N_TOK;
#pragma unroll
      for (int t = 0; t < GSLOT; t++) {
        const int m = gt + 128 * t;
        const bool valid = (t < 15) || (gt < GTAIL);
        const int mc = valid ? m : (N_TOK - 1);
        float d0 = 0.f, d1 = 0.f;
        DOT_BODY(kt4, mc, d0, d1);
        if (valid) { raw0[t] += d0; raw1[t] += d1; }
      }
    }

    // ===== per-group packed reduction of the 4 softmax sums =====
    {
#pragma unroll
      for (int off = 32; off > 0; off >>= 1) {
        ls0 += __shfl_xor(ls0, off, 64);
        ls1 += __shfl_xor(ls1, off, 64);
        lr0 += __shfl_xor(lr0, off, 64);
        lr1 += __shfl_xor(lr1, off, 64);
      }
      __syncthreads();  // also covers s_ec/s_er visibility within group
      if ((tid & 63) == 0) {
        redm[g][wig][0] = ls0;
        redm[g][wig][1] = ls1;
        redm[g][wig][2] = lr0;
        redm[g][wig][3] = lr1;
      }
      __syncthreads();
      ls0 = redm[g][0][0] + redm[g][1][0];
      ls1 = redm[g][0][1] + redm[g][1][1];
      lr0 = redm[g][0][2] + redm[g][1][2];
      lr1 = redm[g][0][3] + redm[g][1][3];
    }
    const float n0c = 0.5f / ls0, n1c = 0.5f / ls1;
    const float n0r = 0.5f / lr0, n1r = 0.5f / lr1;

    // ===== combine, mask, sim += ; attn overwrites s_ec rows =====
#pragma unroll
    for (int t = 0; t < GSLOT; t++) {
      const int m = gt + 128 * t;
      if ((t < 15) || (gt < GTAIL)) {
        float a0 = s_ec[2 * g][m] * n0c + s_er[2 * g][m] * n0r;
        float a1 = s_ec[2 * g + 1][m] * n1c + s_er[2 * g + 1][m] * n1r;
        if (m >= bs && m < bs + 9) {
          if (m != iA) a0 = 0.f;
          if (m != iB) a1 = 0.f;
        }
        s_ec[2 * g][m] = a0;
        s_ec[2 * g + 1][m] = a1;
        sim0[t] += a0;
        sim1[t] += a1;
      }
    }
    __syncthreads();  // all 4 attn rows final

    // ===== attn @ V : two passes over the two pairs, all 256 threads =====
#pragma unroll
    for (int p = 0; p < 2; p++) {
      const int rA = i0 + 2 * p, rB = rA + 1;
      {
        const int g2 = tid & 7, slice = tid >> 3;
        const int m0 = slice * 63;
        const int mend = (m0 + 63 < N_TOK) ? (m0 + 63) : N_TOK;
        float4 aA = {0.f, 0.f, 0.f, 0.f}, aB = {0.f, 0.f, 0.f, 0.f};
        const float4* __restrict__ v4 = (const float4*)v_rm + (size_t)h * N_TOK * 8;
        for (int m = m0; m < mend; m++) {
          const float4 vv = v4[m * 8 + g2];
          const float a0 = s_ec[2 * p][m];
          const float a1 = s_ec[2 * p + 1][m];
          aA.x += a0 * vv.x; aA.y += a0 * vv.y;
          aA.z += a0 * vv.z; aA.w += a0 * vv.w;
          aB.x += a1 * vv.x; aB.y += a1 * vv.y;
          aB.z += a1 * vv.z; aB.w += a1 * vv.w;
        }
        part4[slice][0][g2] = aA;
        part4[slice][1][g2] = aB;
      }
      __syncthreads();
      if (tid < 16) {
        const int q = tid >> 3, gg = tid & 7;
        float4 s = {0.f, 0.f, 0.f, 0.f};
#pragma unroll 8
        for (int sl = 0; sl < 32; sl++) {
          const float4 pv = part4[sl][q][gg];
          s.x += pv.x; s.y += pv.y; s.z += pv.z; s.w += pv.w;
        }
        const int irow = q ? rB : rA;
        *(float4*)(out_x + (size_t)irow * 512 + h * 32 + 4 * gg) = s;
      } else if (tid >= 64 && tid < 128) {
        const int q = (tid - 64) >> 5, d = (tid - 64) & 31;
        const int irow = q ? rB : rA;
        out_x[(size_t)irow * 512 + 256 + h * 32 + d] =
            v_rm[((size_t)h * N_TOK + irow) * HD + d];
      }
      __syncthreads();  // part4 reuse / s_ec reuse next head
    }
  }

  // ===== sim_round2 epilogue, per group from registers =====
#pragma unroll
  for (int qsel = 0; qsel < 2; qsel++) {
    const int irow = qsel ? iB : iA;
    float* __restrict__ sim = qsel ? sim1 : sim0;
    float* __restrict__ raw = qsel ? raw1 : raw0;

    // group max
    float lm = -1e30f;
#pragma unroll
    for (int t = 0; t < GSLOT; t++) {
      if ((t < 15) || (gt < GTAIL)) lm = fmaxf(lm, sim[t] * 0.125f);
    }
#pragma unroll
    for (int off = 32; off > 0; off >>= 1) lm = fmaxf(lm, __shfl_xor(lm, off, 64));
    __syncthreads();
    if ((tid & 63) == 0) redm[g][wig][0] = lm;
    __syncthreads();
    const float M = fmaxf(redm[g][0][0], redm[g][1][0]);

    // exp + group sum
    float ls = 0.f;
#pragma unroll
    for (int t = 0; t < GSLOT; t++) {
      const bool valid = (t < 15) || (gt < GTAIL);
      const float e = valid ? __expf(sim[t] * 0.125f - M) : 0.f;
      sim[t] = e;
      ls += e;
    }
#pragma unroll
    for (int off = 32; off > 0; off >>= 1) ls += __shfl_xor(ls, off, 64);
    __syncthreads();
    if ((tid & 63) == 0) redm[g][wig][1] = ls;
    __syncthreads();
    const float S = redm[g][0][1] + redm[g][1][1];
    const float invS = 1.0f / S;

    // mask + group sum of masked
    float lms = 0.f;
#pragma unroll
    for (int t = 0; t < GSLOT; t++) {
      const bool valid = (t < 15) || (gt < GTAIL);
      const float pv = sim[t] * invS;
      const float mp = (valid && (raw[t] * 0.125f > SIM_TH)) ? pv : 0.f;
      sim[t] = mp;
      lms += mp;
    }
#pragma unroll
    for (int off = 32; off > 0; off >>= 1) lms += __shfl_xor(lms, off, 64);
    __syncthreads();
    if ((tid & 63) == 0) redm[g][wig][2] = lms;
    __syncthreads();
    const float MS = redm[g][0][2] + redm[g][1][2];
    const float invMS = 1.0f / (MS + EPSF);

#pragma unroll
    for (int t = 0; t < GSLOT; t++) {
      const int m = gt + 128 * t;
      if ((t < 15) || (gt < GTAIL)) {
        out_sim[(size_t)irow * N_TOK + m] = sim[t] * invMS;
      }
    }
  }
}

// ---------------------------------------------------------------------------
extern "C" void kernel_launch(void* const* d_in, const int* in_sizes, int n_in,
                              void* d_out, int out_size, void* d_ws,
                              size_t ws_size, hipStream_t stream) {
  const float* x_cls = (const float*)d_in[0];
  const float* x_reg = (const float*)d_in[1];
  const float* W_cls = (const float*)d_in[2];
  const float* W_reg = (const float*)d_in[3];

  float* ws = (float*)d_ws;
  const size_t seg = (size_t)NH * N_TOK * HD;  // 512000 floats
  float* qn_cls = ws;
  float* qn_reg = qn_cls + seg;
  float* kct = qn_reg + seg;
  float* krt = kct + seg;
  float* vnt = krt + seg;
  float* v_rm = vnt + seg;

  dim3 g1(500, 2);
  qkv_norm_kernel<<<g1, 256, 0, stream>>>(x_cls, x_reg, W_cls, W_reg, qn_cls,
                                          qn_reg, kct, krt, vnt, v_rm);

  float* out_x = (float*)d_out;                  // [2000, 512]
  float* out_sim = out_x + (size_t)N_TOK * 512;  // [2000, 2000]
  attn7_kernel<<<500, 256, 0, stream>>>(qn_cls, qn_reg, kct, krt, vnt, v_rm,
                                        out_x, out_sim);
}

// Round 8
// 1283.854 us; speedup vs baseline: 1.4074x; 1.4074x over previous
//
#include <hip/hip_runtime.h>
#include <math.h>

#define N_TOK 2000
#define NH 8
#define HD 32
#define SCALE 25.0f
#define SIM_TH 0.75f
#define EPSF 1e-8f
#define NSLOT 8   // ceil(2000/256)
#define NTAIL 208 // valid lanes in slot 7: 2000 - 7*256

// force a uniform value into an SGPR so dot-loop FMAs are v_fmac(v, s, v)
__device__ __forceinline__ float rfl(float x) {
  return __int_as_float(__builtin_amdgcn_readfirstlane(__float_as_int(x)));
}

__device__ __forceinline__ float block_max256(float v, float* red) {
#pragma unroll
  for (int off = 32; off > 0; off >>= 1) v = fmaxf(v, __shfl_xor(v, off, 64));
  __syncthreads();
  if ((threadIdx.x & 63) == 0) red[threadIdx.x >> 6] = v;
  __syncthreads();
  return fmaxf(fmaxf(red[0], red[1]), fmaxf(red[2], red[3]));
}
__device__ __forceinline__ float block_sum256(float v, float* red) {
#pragma unroll
  for (int off = 32; off > 0; off >>= 1) v += __shfl_xor(v, off, 64);
  __syncthreads();
  if ((threadIdx.x & 63) == 0) red[threadIdx.x >> 6] = v;
  __syncthreads();
  return (red[0] + red[1]) + (red[2] + red[3]);
}

// dot of two uniform q[32] (SGPR) against one K row. All 8 16B loads issued
// upfront into DISTINCT registers (no reuse serialization). This exact shape
// was spill-free in round 2 (VGPR 168) when phases are fenced by their block
// reductions; round 6's spill came from removing the fences, not from DOT8.
#define DOT8(kt4, mc, d0, d1)                                             \
  {                                                                       \
    float4 kv[8];                                                         \
    _Pragma("unroll") for (int g_ = 0; g_ < 8; g_++) kv[g_] =             \
        kt4[g_ * N_TOK + (mc)];                                           \
    _Pragma("unroll") for (int g_ = 0; g_ < 8; g_++) {                    \
      d0 += q0[4 * g_] * kv[g_].x + q0[4 * g_ + 1] * kv[g_].y +           \
            q0[4 * g_ + 2] * kv[g_].z + q0[4 * g_ + 3] * kv[g_].w;        \
      d1 += q1[4 * g_] * kv[g_].x + q1[4 * g_ + 1] * kv[g_].y +           \
            q1[4 * g_ + 2] * kv[g_].z + q1[4 * g_ + 3] * kv[g_].w;        \
    }                                                                     \
  }

// ---------------------------------------------------------------------------
// Kernel 1: QKV projection + l2norm (unchanged; ~70 us).
// grid = (500, 2), block = 256
// ---------------------------------------------------------------------------
__global__ __launch_bounds__(256) void qkv_norm_kernel(
    const float* __restrict__ x_cls, const float* __restrict__ x_reg,
    const float* __restrict__ W_cls, const float* __restrict__ W_reg,
    float* __restrict__ qn_cls, float* __restrict__ qn_reg,
    float* __restrict__ kct, float* __restrict__ krt,
    float* __restrict__ vnt, float* __restrict__ v_rm) {
  __shared__ float xs[4][256];
  __shared__ float res[4][768];
  __shared__ float inv_norm[96];

  const int n0 = blockIdx.x * 4;
  const int which = blockIdx.y;
  const int tid = threadIdx.x;
  const float* __restrict__ x = which ? x_reg : x_cls;
  const float* __restrict__ W = which ? W_reg : W_cls;

#pragma unroll
  for (int r = 0; r < 4; r++) xs[r][tid] = x[(n0 + r) * 256 + tid];
  __syncthreads();

  float acc[4][3];
#pragma unroll
  for (int r = 0; r < 4; r++) acc[r][0] = acc[r][1] = acc[r][2] = 0.f;

  for (int k = 0; k < 256; k++) {
    const float* __restrict__ wr = W + k * 768;
    const float w0 = wr[tid], w1 = wr[tid + 256], w2 = wr[tid + 512];
#pragma unroll
    for (int r = 0; r < 4; r++) {
      const float xv = xs[r][k];
      acc[r][0] += xv * w0;
      acc[r][1] += xv * w1;
      acc[r][2] += xv * w2;
    }
  }
#pragma unroll
  for (int r = 0; r < 4; r++) {
    res[r][tid] = acc[r][0];
    res[r][tid + 256] = acc[r][1];
    res[r][tid + 512] = acc[r][2];
  }
  __syncthreads();

  if (tid < 96) {
    const int r = tid / 24, grp = tid % 24;
    float ss = 0.f;
#pragma unroll
    for (int d = 0; d < HD; d++) {
      const float v = res[r][grp * 32 + d];
      ss += v * v;
    }
    inv_norm[tid] = 1.0f / (sqrtf(ss) + EPSF);
  }
  __syncthreads();

#pragma unroll
  for (int j = 0; j < 3; j++) {
    const int c = tid + j * 256;
    const int qkv = c >> 8, grp = c >> 5;
    const int h = grp & 7, d = c & 31;
    const int g = d >> 2, comp = d & 3;
#pragma unroll
    for (int r = 0; r < 4; r++) {
      const int n = n0 + r;
      const float val = res[r][c];
      const float nval = val * inv_norm[r * 24 + grp];
      if (qkv == 0) {
        (which ? qn_reg : qn_cls)[(h * N_TOK + n) * HD + d] = nval;
      } else if (qkv == 1) {
        (which ? krt : kct)[((h * 8 + g) * N_TOK + n) * 4 + comp] = nval;
      } else if (which == 0) {
        v_rm[(h * N_TOK + n) * HD + d] = val;
        vnt[((h * 8 + g) * N_TOK + n) * 4 + comp] = nval;
      }
    }
  }
}

// ---------------------------------------------------------------------------
// Kernel 2: round-5 structure (2 queries/block, fixed-shift softmax, sim/raw/
// er register slots, per-phase block reductions as scheduling fences) plus
// exactly two deltas: (a) DOT8 — 8 loads upfront, distinct regs, kills the
// intra-iter dependency serialization; (b) head rotation by blockIdx so
// blocks sharing an XCD walk the same head (working set ~3MB fits 4MB L2).
// grid = 1000, block = 256
// ---------------------------------------------------------------------------
__global__ __launch_bounds__(256) void attn8_kernel(
    const float* __restrict__ qn_cls, const float* __restrict__ qn_reg,
    const float* __restrict__ kct, const float* __restrict__ krt,
    const float* __restrict__ vnt, const float* __restrict__ v_rm,
    float* __restrict__ out_x, float* __restrict__ out_sim) {
  __shared__ float s_attn[2 * N_TOK];
  __shared__ float4 part4[32][2][8];
  __shared__ float red[4];

  const int tid = threadIdx.x;
  const int i0 = blockIdx.x * 2;
  const int i1 = i0 + 1;
  const int bs = (i0 / 10) * 10;  // i0 even -> i0,i1 share the same decade

  float sim0[NSLOT], sim1[NSLOT], raw0[NSLOT], raw1[NSLOT];
#pragma unroll
  for (int t = 0; t < NSLOT; t++) {
    sim0[t] = 0.f; sim1[t] = 0.f; raw0[t] = 0.f; raw1[t] = 0.f;
  }

  float q0[HD], q1[HD];          // wave-uniform -> SGPRs
  float er0[NSLOT], er1[NSLOT];  // reg-stream exp values

  for (int hh = 0; hh < NH; hh++) {
    const int h = (blockIdx.x + hh) & 7;  // XCD-local head schedule

    // ===== phase C: cls scores -> e = exp(s-25) -> s_attn (unnormalized) ===
    {
      const float* __restrict__ p0 = qn_cls + (size_t)(h * N_TOK + i0) * HD;
      const float* __restrict__ p1 = qn_cls + (size_t)(h * N_TOK + i1) * HD;
#pragma unroll
      for (int d = 0; d < HD; d++) { q0[d] = rfl(p0[d]); q1[d] = rfl(p1[d]); }
    }
    float ls0 = 0.f, ls1 = 0.f;
    {
      const float4* __restrict__ kt4 = (const float4*)kct + (size_t)h * 8 * N_TOK;
#pragma unroll
      for (int t = 0; t < NSLOT; t++) {
        const int m = tid + 256 * t;
        const bool valid = (t < 7) || (tid < NTAIL);
        const int mc = valid ? m : (N_TOK - 1);
        float d0 = 0.f, d1 = 0.f;
        DOT8(kt4, mc, d0, d1);
        const float e0 = valid ? __expf(d0 * SCALE - SCALE) : 0.f;
        const float e1 = valid ? __expf(d1 * SCALE - SCALE) : 0.f;
        ls0 += e0; ls1 += e1;
        if (valid) {
          s_attn[m] = e0;
          s_attn[N_TOK + m] = e1;
        }
      }
    }
    const float S0c = block_sum256(ls0, red);
    const float S1c = block_sum256(ls1, red);
    const float n0c = 0.5f / S0c, n1c = 0.5f / S1c;

    // ===== phase R: reg scores -> er regs =====
    {
      const float* __restrict__ p0 = qn_reg + (size_t)(h * N_TOK + i0) * HD;
      const float* __restrict__ p1 = qn_reg + (size_t)(h * N_TOK + i1) * HD;
#pragma unroll
      for (int d = 0; d < HD; d++) { q0[d] = rfl(p0[d]); q1[d] = rfl(p1[d]); }
    }
    float lr0 = 0.f, lr1 = 0.f;
    {
      const float4* __restrict__ kt4 = (const float4*)krt + (size_t)h * 8 * N_TOK;
#pragma unroll
      for (int t = 0; t < NSLOT; t++) {
        const int m = tid + 256 * t;
        const bool valid = (t < 7) || (tid < NTAIL);
        const int mc = valid ? m : (N_TOK - 1);
        float d0 = 0.f, d1 = 0.f;
        DOT8(kt4, mc, d0, d1);
        const float e0 = valid ? __expf(d0 * SCALE - SCALE) : 0.f;
        const float e1 = valid ? __expf(d1 * SCALE - SCALE) : 0.f;
        er0[t] = e0; er1[t] = e1;
        lr0 += e0; lr1 += e1;
      }
    }
    const float S0r = block_sum256(lr0, red);
    const float S1r = block_sum256(lr1, red);
    const float n0r = 0.5f / S0r, n1r = 0.5f / S1r;

    // ===== combine, mask, sim += =====
#pragma unroll
    for (int t = 0; t < NSLOT; t++) {
      const int m = tid + 256 * t;
      if ((t < 7) || (tid < NTAIL)) {
        float a0 = s_attn[m] * n0c + er0[t] * n0r;
        float a1 = s_attn[N_TOK + m] * n1c + er1[t] * n1r;
        if (m >= bs && m < bs + 9) {
          if (m != i0) a0 = 0.f;
          if (m != i1) a1 = 0.f;
        }
        s_attn[m] = a0;
        s_attn[N_TOK + m] = a1;
        sim0[t] += a0;
        sim1[t] += a1;
      }
    }

    // ===== phase V: vn cosine -> raw += =====
    {
#pragma unroll
      for (int d = 0; d < HD; d++) {
        const int g = d >> 2, comp = d & 3;
        q0[d] = rfl(vnt[((size_t)(h * 8 + g) * N_TOK + i0) * 4 + comp]);
        q1[d] = rfl(vnt[((size_t)(h * 8 + g) * N_TOK + i1) * 4 + comp]);
      }
      const float4* __restrict__ kt4 = (const float4*)vnt + (size_t)h * 8 * N_TOK;
#pragma unroll
      for (int t = 0; t < NSLOT; t++) {
        const int m = tid + 256 * t;
        const bool valid = (t < 7) || (tid < NTAIL);
        const int mc = valid ? m : (N_TOK - 1);
        float d0 = 0.f, d1 = 0.f;
        DOT8(kt4, mc, d0, d1);
        if (valid) { raw0[t] += d0; raw1[t] += d1; }
      }
    }
    __syncthreads();  // s_attn final for this head

    // ===== attn @ V =====
    {
      const int g2 = tid & 7, slice = tid >> 3;
      const int m0 = slice * 63;
      const int mend = (m0 + 63 < N_TOK) ? (m0 + 63) : N_TOK;
      float4 a0acc = {0.f, 0.f, 0.f, 0.f}, a1acc = {0.f, 0.f, 0.f, 0.f};
      const float4* __restrict__ v4 = (const float4*)v_rm + (size_t)h * N_TOK * 8;
      for (int m = m0; m < mend; m++) {
        const float4 vv = v4[m * 8 + g2];
        const float a0 = s_attn[m];
        const float a1 = s_attn[N_TOK + m];
        a0acc.x += a0 * vv.x; a0acc.y += a0 * vv.y;
        a0acc.z += a0 * vv.z; a0acc.w += a0 * vv.w;
        a1acc.x += a1 * vv.x; a1acc.y += a1 * vv.y;
        a1acc.z += a1 * vv.z; a1acc.w += a1 * vv.w;
      }
      part4[slice][0][g2] = a0acc;
      part4[slice][1][g2] = a1acc;
    }
    __syncthreads();
    if (tid < 16) {
      const int q = tid >> 3, g = tid & 7;
      float4 s = {0.f, 0.f, 0.f, 0.f};
#pragma unroll 8
      for (int sl = 0; sl < 32; sl++) {
        const float4 p = part4[sl][q][g];
        s.x += p.x; s.y += p.y; s.z += p.z; s.w += p.w;
      }
      const int irow = q ? i1 : i0;
      *(float4*)(out_x + (size_t)irow * 512 + h * 32 + 4 * g) = s;
    } else if (tid >= 64 && tid < 128) {
      const int q = (tid - 64) >> 5, d = (tid - 64) & 31;
      const int irow = q ? i1 : i0;
      out_x[(size_t)irow * 512 + 256 + h * 32 + d] =
          v_rm[((size_t)h * N_TOK + irow) * HD + d];
    }
    __syncthreads();  // protect s_attn/part4 before next head
  }

  // ===== sim_round2 epilogue, from registers =====
#pragma unroll
  for (int q = 0; q < 2; q++) {
    const int irow = q ? i1 : i0;
    float* __restrict__ sim = q ? sim1 : sim0;
    float* __restrict__ raw = q ? raw1 : raw0;

    float lm = -1e30f;
#pragma unroll
    for (int t = 0; t < NSLOT; t++) {
      if ((t < 7) || (tid < NTAIL)) lm = fmaxf(lm, sim[t] * 0.125f);
    }
    const float M = block_max256(lm, red);

    float ls = 0.f;
#pragma unroll
    for (int t = 0; t < NSLOT; t++) {
      const bool valid = (t < 7) || (tid < NTAIL);
      const float e = valid ? __expf(sim[t] * 0.125f - M) : 0.f;
      sim[t] = e;
      ls += e;
    }
    const float S = block_sum256(ls, red);
    const float invS = 1.0f / S;

    float lms = 0.f;
#pragma unroll
    for (int t = 0; t < NSLOT; t++) {
      const bool valid = (t < 7) || (tid < NTAIL);
      const float p = sim[t] * invS;
      const float mp = (valid && (raw[t] * 0.125f > SIM_TH)) ? p : 0.f;
      sim[t] = mp;
      lms += mp;
    }
    const float MS = block_sum256(lms, red);
    const float invMS = 1.0f / (MS + EPSF);

#pragma unroll
    for (int t = 0; t < NSLOT; t++) {
      const int m = tid + 256 * t;
      if ((t < 7) || (tid < NTAIL)) {
        out_sim[(size_t)irow * N_TOK + m] = sim[t] * invMS;
      }
    }
  }
}

// ---------------------------------------------------------------------------
extern "C" void kernel_launch(void* const* d_in, const int* in_sizes, int n_in,
                              void* d_out, int out_size, void* d_ws,
                              size_t ws_size, hipStream_t stream) {
  const float* x_cls = (const float*)d_in[0];
  const float* x_reg = (const float*)d_in[1];
  const float* W_cls = (const float*)d_in[2];
  const float* W_reg = (const float*)d_in[3];

  float* ws = (float*)d_ws;
  const size_t seg = (size_t)NH * N_TOK * HD;  // 512000 floats
  float* qn_cls = ws;
  float* qn_reg = qn_cls + seg;
  float* kct = qn_reg + seg;
  float* krt = kct + seg;
  float* vnt = krt + seg;
  float* v_rm = vnt + seg;

  dim3 g1(500, 2);
  qkv_norm_kernel<<<g1, 256, 0, stream>>>(x_cls, x_reg, W_cls, W_reg, qn_cls,
                                          qn_reg, kct, krt, vnt, v_rm);

  float* out_x = (float*)d_out;                  // [2000, 512]
  float* out_sim = out_x + (size_t)N_TOK * 512;  // [2000, 2000]
  attn8_kernel<<<1000, 256, 0, stream>>>(qn_cls, qn_reg, kct, krt, vnt, v_rm,
                                         out_x, out_sim);
}

// Round 9
// 1270.120 us; speedup vs baseline: 1.4226x; 1.0108x over previous
//
#include <hip/hip_runtime.h>
#include <math.h>

#define N_TOK 2000
#define NH 8
#define HD 32
#define SCALE 25.0f
#define SIM_TH 0.75f
#define EPSF 1e-8f
#define NSLOT 8   // ceil(2000/256)
#define NTAIL 208 // valid lanes in slot 7: 2000 - 7*256

// force a uniform value into an SGPR so dot-loop FMAs are v_fmac(v, s, v)
__device__ __forceinline__ float rfl(float x) {
  return __int_as_float(__builtin_amdgcn_readfirstlane(__float_as_int(x)));
}

__device__ __forceinline__ float block_max256(float v, float* red) {
#pragma unroll
  for (int off = 32; off > 0; off >>= 1) v = fmaxf(v, __shfl_xor(v, off, 64));
  __syncthreads();
  if ((threadIdx.x & 63) == 0) red[threadIdx.x >> 6] = v;
  __syncthreads();
  return fmaxf(fmaxf(red[0], red[1]), fmaxf(red[2], red[3]));
}
__device__ __forceinline__ float block_sum256(float v, float* red) {
#pragma unroll
  for (int off = 32; off > 0; off >>= 1) v += __shfl_xor(v, off, 64);
  __syncthreads();
  if ((threadIdx.x & 63) == 0) red[threadIdx.x >> 6] = v;
  __syncthreads();
  return (red[0] + red[1]) + (red[2] + red[3]);
}

// dot of two uniform q[32] (SGPR) against one K row. All 8 16B loads issued
// upfront into DISTINCT registers (max MLP; spill-free at current state size).
#define DOT8(kt4, mc, d0, d1)                                             \
  {                                                                       \
    float4 kv[8];                                                         \
    _Pragma("unroll") for (int g_ = 0; g_ < 8; g_++) kv[g_] =             \
        kt4[g_ * N_TOK + (mc)];                                           \
    _Pragma("unroll") for (int g_ = 0; g_ < 8; g_++) {                    \
      d0 += q0[4 * g_] * kv[g_].x + q0[4 * g_ + 1] * kv[g_].y +           \
            q0[4 * g_ + 2] * kv[g_].z + q0[4 * g_ + 3] * kv[g_].w;        \
      d1 += q1[4 * g_] * kv[g_].x + q1[4 * g_ + 1] * kv[g_].y +           \
            q1[4 * g_ + 2] * kv[g_].z + q1[4 * g_ + 3] * kv[g_].w;        \
    }                                                                     \
  }

// ---------------------------------------------------------------------------
// Kernel 1: QKV projection + l2norm (unchanged; ~70 us).
// grid = (500, 2), block = 256
// ---------------------------------------------------------------------------
__global__ __launch_bounds__(256) void qkv_norm_kernel(
    const float* __restrict__ x_cls, const float* __restrict__ x_reg,
    const float* __restrict__ W_cls, const float* __restrict__ W_reg,
    float* __restrict__ qn_cls, float* __restrict__ qn_reg,
    float* __restrict__ kct, float* __restrict__ krt,
    float* __restrict__ vnt, float* __restrict__ v_rm) {
  __shared__ float xs[4][256];
  __shared__ float res[4][768];
  __shared__ float inv_norm[96];

  const int n0 = blockIdx.x * 4;
  const int which = blockIdx.y;
  const int tid = threadIdx.x;
  const float* __restrict__ x = which ? x_reg : x_cls;
  const float* __restrict__ W = which ? W_reg : W_cls;

#pragma unroll
  for (int r = 0; r < 4; r++) xs[r][tid] = x[(n0 + r) * 256 + tid];
  __syncthreads();

  float acc[4][3];
#pragma unroll
  for (int r = 0; r < 4; r++) acc[r][0] = acc[r][1] = acc[r][2] = 0.f;

  for (int k = 0; k < 256; k++) {
    const float* __restrict__ wr = W + k * 768;
    const float w0 = wr[tid], w1 = wr[tid + 256], w2 = wr[tid + 512];
#pragma unroll
    for (int r = 0; r < 4; r++) {
      const float xv = xs[r][k];
      acc[r][0] += xv * w0;
      acc[r][1] += xv * w1;
      acc[r][2] += xv * w2;
    }
  }
#pragma unroll
  for (int r = 0; r < 4; r++) {
    res[r][tid] = acc[r][0];
    res[r][tid + 256] = acc[r][1];
    res[r][tid + 512] = acc[r][2];
  }
  __syncthreads();

  if (tid < 96) {
    const int r = tid / 24, grp = tid % 24;
    float ss = 0.f;
#pragma unroll
    for (int d = 0; d < HD; d++) {
      const float v = res[r][grp * 32 + d];
      ss += v * v;
    }
    inv_norm[tid] = 1.0f / (sqrtf(ss) + EPSF);
  }
  __syncthreads();

#pragma unroll
  for (int j = 0; j < 3; j++) {
    const int c = tid + j * 256;
    const int qkv = c >> 8, grp = c >> 5;
    const int h = grp & 7, d = c & 31;
    const int g = d >> 2, comp = d & 3;
#pragma unroll
    for (int r = 0; r < 4; r++) {
      const int n = n0 + r;
      const float val = res[r][c];
      const float nval = val * inv_norm[r * 24 + grp];
      if (qkv == 0) {
        (which ? qn_reg : qn_cls)[(h * N_TOK + n) * HD + d] = nval;
      } else if (qkv == 1) {
        (which ? krt : kct)[((h * 8 + g) * N_TOK + n) * 4 + comp] = nval;
      } else if (which == 0) {
        v_rm[(h * N_TOK + n) * HD + d] = val;
        vnt[((h * 8 + g) * N_TOK + n) * 4 + comp] = nval;
      }
    }
  }
}

// ---------------------------------------------------------------------------
// Kernel 2: round-8 structure with ONE delta: er exp-values move from
// register slots (16 VGPRs) to LDS, placed in a UNION with part4 (disjoint
// lifetimes within a head iteration, fenced by the existing barriers).
// Rationale: round-8 VGPR=176 is 6 regs above the 3-waves/SIMD occupancy
// step at <=170 (pool 512). Shaving 16 regs buys +50% wave concurrency on a
// latency-bound kernel with zero precision change. No launch-bounds clamp
// (the (256,N) clamp spilled in rounds 3/4). LDS ~32.1 KB.
// grid = 1000, block = 256
// ---------------------------------------------------------------------------
__global__ __launch_bounds__(256) void attn9_kernel(
    const float* __restrict__ qn_cls, const float* __restrict__ qn_reg,
    const float* __restrict__ kct, const float* __restrict__ krt,
    const float* __restrict__ vnt, const float* __restrict__ v_rm,
    float* __restrict__ out_x, float* __restrict__ out_sim) {
  __shared__ float s_attn[2 * N_TOK];
  __shared__ float s_union[2 * N_TOK];  // er (phases C/R->combine) / part4 (PV)
  __shared__ float red[4];

  float* __restrict__ s_er = s_union;            // [2*N_TOK]
  float4* __restrict__ part4 = (float4*)s_union; // [32][2][8] = 8 KB

  const int tid = threadIdx.x;
  const int i0 = blockIdx.x * 2;
  const int i1 = i0 + 1;
  const int bs = (i0 / 10) * 10;  // i0 even -> i0,i1 share the same decade

  float sim0[NSLOT], sim1[NSLOT], raw0[NSLOT], raw1[NSLOT];
#pragma unroll
  for (int t = 0; t < NSLOT; t++) {
    sim0[t] = 0.f; sim1[t] = 0.f; raw0[t] = 0.f; raw1[t] = 0.f;
  }

  float q0[HD], q1[HD];  // wave-uniform -> SGPRs

  for (int hh = 0; hh < NH; hh++) {
    const int h = (blockIdx.x + hh) & 7;  // XCD-local head schedule

    // ===== phase C: cls scores -> e = exp(s-25) -> s_attn (unnormalized) ===
    {
      const float* __restrict__ p0 = qn_cls + (size_t)(h * N_TOK + i0) * HD;
      const float* __restrict__ p1 = qn_cls + (size_t)(h * N_TOK + i1) * HD;
#pragma unroll
      for (int d = 0; d < HD; d++) { q0[d] = rfl(p0[d]); q1[d] = rfl(p1[d]); }
    }
    float ls0 = 0.f, ls1 = 0.f;
    {
      const float4* __restrict__ kt4 = (const float4*)kct + (size_t)h * 8 * N_TOK;
#pragma unroll
      for (int t = 0; t < NSLOT; t++) {
        const int m = tid + 256 * t;
        const bool valid = (t < 7) || (tid < NTAIL);
        const int mc = valid ? m : (N_TOK - 1);
        float d0 = 0.f, d1 = 0.f;
        DOT8(kt4, mc, d0, d1);
        const float e0 = valid ? __expf(d0 * SCALE - SCALE) : 0.f;
        const float e1 = valid ? __expf(d1 * SCALE - SCALE) : 0.f;
        ls0 += e0; ls1 += e1;
        if (valid) {
          s_attn[m] = e0;
          s_attn[N_TOK + m] = e1;
        }
      }
    }
    const float S0c = block_sum256(ls0, red);
    const float S1c = block_sum256(ls1, red);
    const float n0c = 0.5f / S0c, n1c = 0.5f / S1c;

    // ===== phase R: reg scores -> s_er (own slots only; no barrier needed) ==
    {
      const float* __restrict__ p0 = qn_reg + (size_t)(h * N_TOK + i0) * HD;
      const float* __restrict__ p1 = qn_reg + (size_t)(h * N_TOK + i1) * HD;
#pragma unroll
      for (int d = 0; d < HD; d++) { q0[d] = rfl(p0[d]); q1[d] = rfl(p1[d]); }
    }
    float lr0 = 0.f, lr1 = 0.f;
    {
      const float4* __restrict__ kt4 = (const float4*)krt + (size_t)h * 8 * N_TOK;
#pragma unroll
      for (int t = 0; t < NSLOT; t++) {
        const int m = tid + 256 * t;
        const bool valid = (t < 7) || (tid < NTAIL);
        const int mc = valid ? m : (N_TOK - 1);
        float d0 = 0.f, d1 = 0.f;
        DOT8(kt4, mc, d0, d1);
        const float e0 = valid ? __expf(d0 * SCALE - SCALE) : 0.f;
        const float e1 = valid ? __expf(d1 * SCALE - SCALE) : 0.f;
        lr0 += e0; lr1 += e1;
        if (valid) {
          s_er[m] = e0;
          s_er[N_TOK + m] = e1;
        }
      }
    }
    const float S0r = block_sum256(lr0, red);
    const float S1r = block_sum256(lr1, red);
    const float n0r = 0.5f / S0r, n1r = 0.5f / S1r;

    // ===== combine, mask, sim += (reads own s_er slots) =====
#pragma unroll
    for (int t = 0; t < NSLOT; t++) {
      const int m = tid + 256 * t;
      if ((t < 7) || (tid < NTAIL)) {
        float a0 = s_attn[m] * n0c + s_er[m] * n0r;
        float a1 = s_attn[N_TOK + m] * n1c + s_er[N_TOK + m] * n1r;
        if (m >= bs && m < bs + 9) {
          if (m != i0) a0 = 0.f;
          if (m != i1) a1 = 0.f;
        }
        s_attn[m] = a0;
        s_attn[N_TOK + m] = a1;
        sim0[t] += a0;
        sim1[t] += a1;
      }
    }

    // ===== phase V: vn cosine -> raw += =====
    {
#pragma unroll
      for (int d = 0; d < HD; d++) {
        const int g = d >> 2, comp = d & 3;
        q0[d] = rfl(vnt[((size_t)(h * 8 + g) * N_TOK + i0) * 4 + comp]);
        q1[d] = rfl(vnt[((size_t)(h * 8 + g) * N_TOK + i1) * 4 + comp]);
      }
      const float4* __restrict__ kt4 = (const float4*)vnt + (size_t)h * 8 * N_TOK;
#pragma unroll
      for (int t = 0; t < NSLOT; t++) {
        const int m = tid + 256 * t;
        const bool valid = (t < 7) || (tid < NTAIL);
        const int mc = valid ? m : (N_TOK - 1);
        float d0 = 0.f, d1 = 0.f;
        DOT8(kt4, mc, d0, d1);
        if (valid) { raw0[t] += d0; raw1[t] += d1; }
      }
    }
    __syncthreads();  // s_attn final; all s_er reads done -> part4 may reuse

    // ===== attn @ V (part4 overlays s_er storage) =====
    {
      const int g2 = tid & 7, slice = tid >> 3;
      const int m0 = slice * 63;
      const int mend = (m0 + 63 < N_TOK) ? (m0 + 63) : N_TOK;
      float4 a0acc = {0.f, 0.f, 0.f, 0.f}, a1acc = {0.f, 0.f, 0.f, 0.f};
      const float4* __restrict__ v4 = (const float4*)v_rm + (size_t)h * N_TOK * 8;
      for (int m = m0; m < mend; m++) {
        const float4 vv = v4[m * 8 + g2];
        const float a0 = s_attn[m];
        const float a1 = s_attn[N_TOK + m];
        a0acc.x += a0 * vv.x; a0acc.y += a0 * vv.y;
        a0acc.z += a0 * vv.z; a0acc.w += a0 * vv.w;
        a1acc.x += a1 * vv.x; a1acc.y += a1 * vv.y;
        a1acc.z += a1 * vv.z; a1acc.w += a1 * vv.w;
      }
      part4[(slice * 2 + 0) * 8 + g2] = a0acc;
      part4[(slice * 2 + 1) * 8 + g2] = a1acc;
    }
    __syncthreads();
    if (tid < 16) {
      const int q = tid >> 3, g = tid & 7;
      float4 s = {0.f, 0.f, 0.f, 0.f};
#pragma unroll 8
      for (int sl = 0; sl < 32; sl++) {
        const float4 p = part4[(sl * 2 + q) * 8 + g];
        s.x += p.x; s.y += p.y; s.z += p.z; s.w += p.w;
      }
      const int irow = q ? i1 : i0;
      *(float4*)(out_x + (size_t)irow * 512 + h * 32 + 4 * g) = s;
    } else if (tid >= 64 && tid < 128) {
      const int q = (tid - 64) >> 5, d = (tid - 64) & 31;
      const int irow = q ? i1 : i0;
      out_x[(size_t)irow * 512 + 256 + h * 32 + d] =
          v_rm[((size_t)h * N_TOK + irow) * HD + d];
    }
    __syncthreads();  // part4 reads done -> s_er may reuse next head
  }

  // ===== sim_round2 epilogue, from registers =====
#pragma unroll
  for (int q = 0; q < 2; q++) {
    const int irow = q ? i1 : i0;
    float* __restrict__ sim = q ? sim1 : sim0;
    float* __restrict__ raw = q ? raw1 : raw0;

    float lm = -1e30f;
#pragma unroll
    for (int t = 0; t < NSLOT; t++) {
      if ((t < 7) || (tid < NTAIL)) lm = fmaxf(lm, sim[t] * 0.125f);
    }
    const float M = block_max256(lm, red);

    float ls = 0.f;
#pragma unroll
    for (int t = 0; t < NSLOT; t++) {
      const bool valid = (t < 7) || (tid < NTAIL);
      const float e = valid ? __expf(sim[t] * 0.125f - M) : 0.f;
      sim[t] = e;
      ls += e;
    }
    const float S = block_sum256(ls, red);
    const float invS = 1.0f / S;

    float lms = 0.f;
#pragma unroll
    for (int t = 0; t < NSLOT; t++) {
      const bool valid = (t < 7) || (tid < NTAIL);
      const float p = sim[t] * invS;
      const float mp = (valid && (raw[t] * 0.125f > SIM_TH)) ? p : 0.f;
      sim[t] = mp;
      lms += mp;
    }
    const float MS = block_sum256(lms, red);
    const float invMS = 1.0f / (MS + EPSF);

#pragma unroll
    for (int t = 0; t < NSLOT; t++) {
      const int m = tid + 256 * t;
      if ((t < 7) || (tid < NTAIL)) {
        out_sim[(size_t)irow * N_TOK + m] = sim[t] * invMS;
      }
    }
  }
}

// ---------------------------------------------------------------------------
extern "C" void kernel_launch(void* const* d_in, const int* in_sizes, int n_in,
                              void* d_out, int out_size, void* d_ws,
                              size_t ws_size, hipStream_t stream) {
  const float* x_cls = (const float*)d_in[0];
  const float* x_reg = (const float*)d_in[1];
  const float* W_cls = (const float*)d_in[2];
  const float* W_reg = (const float*)d_in[3];

  float* ws = (float*)d_ws;
  const size_t seg = (size_t)NH * N_TOK * HD;  // 512000 floats
  float* qn_cls = ws;
  float* qn_reg = qn_cls + seg;
  float* kct = qn_reg + seg;
  float* krt = kct + seg;
  float* vnt = krt + seg;
  float* v_rm = vnt + seg;

  dim3 g1(500, 2);
  qkv_norm_kernel<<<g1, 256, 0, stream>>>(x_cls, x_reg, W_cls, W_reg, qn_cls,
                                          qn_reg, kct, krt, vnt, v_rm);

  float* out_x = (float*)d_out;                  // [2000, 512]
  float* out_sim = out_x + (size_t)N_TOK * 512;  // [2000, 2000]
  attn9_kernel<<<1000, 256, 0, stream>>>(qn_cls, qn_reg, kct, krt, vnt, v_rm,
                                         out_x, out_sim);
}

// Round 10
// 555.022 us; speedup vs baseline: 3.2555x; 2.2884x over previous
//
#include <hip/hip_runtime.h>
#include <math.h>

#define N_TOK 2000
#define NH 8
#define HD 32
#define SCALE 25.0f
#define SIM_TH 0.75f
#define EPSF 1e-8f
#define NSLOT 8   // ceil(2000/256)
#define NTAIL 208 // valid lanes in slot 7: 2000 - 7*256

typedef _Float16 half2_t __attribute__((ext_vector_type(2)));

// force a uniform value into an SGPR
__device__ __forceinline__ float rfl(float x) {
  return __int_as_float(__builtin_amdgcn_readfirstlane(__float_as_int(x)));
}
__device__ __forceinline__ unsigned rflu(unsigned u) {
  return (unsigned)__builtin_amdgcn_readfirstlane((int)u);
}
__device__ __forceinline__ half2_t u2h(unsigned u) {
  return __builtin_bit_cast(half2_t, u);
}

// f32 += f16x2 . f16x2 (v_dot2_f32_f16; products exact, fp32 accumulate)
__device__ __forceinline__ float fdot2f(unsigned a, unsigned b, float c) {
#if __has_builtin(__builtin_amdgcn_fdot2)
  return __builtin_amdgcn_fdot2(u2h(a), u2h(b), c, false);
#else
  const half2_t ha = u2h(a), hb = u2h(b);
  return c + (float)ha.x * (float)hb.x + (float)ha.y * (float)hb.y;
#endif
}

__device__ __forceinline__ float block_max256(float v, float* red) {
#pragma unroll
  for (int off = 32; off > 0; off >>= 1) v = fmaxf(v, __shfl_xor(v, off, 64));
  __syncthreads();
  if ((threadIdx.x & 63) == 0) red[threadIdx.x >> 6] = v;
  __syncthreads();
  return fmaxf(fmaxf(red[0], red[1]), fmaxf(red[2], red[3]));
}
__device__ __forceinline__ float block_sum256(float v, float* red) {
#pragma unroll
  for (int off = 32; off > 0; off >>= 1) v += __shfl_xor(v, off, 64);
  __syncthreads();
  if ((threadIdx.x & 63) == 0) red[threadIdx.x >> 6] = v;
  __syncthreads();
  return (red[0] + red[1]) + (red[2] + red[3]);
}

// dot of two uniform packed-f16 q[16xhalf2] (SGPR) vs one f16 K row:
// 4 uint4 loads (16 VGPRs in flight) + 32 fdot2.
#define DOT_F16(kt4, mc, d0, d1)                                          \
  {                                                                       \
    uint4 kv[4];                                                          \
    _Pragma("unroll") for (int g_ = 0; g_ < 4; g_++) kv[g_] =             \
        kt4[g_ * N_TOK + (mc)];                                           \
    _Pragma("unroll") for (int g_ = 0; g_ < 4; g_++) {                    \
      d0 = fdot2f(kv[g_].x, qp0[4 * g_ + 0], d0);                         \
      d0 = fdot2f(kv[g_].y, qp0[4 * g_ + 1], d0);                         \
      d0 = fdot2f(kv[g_].z, qp0[4 * g_ + 2], d0);                         \
      d0 = fdot2f(kv[g_].w, qp0[4 * g_ + 3], d0);                         \
      d1 = fdot2f(kv[g_].x, qp1[4 * g_ + 0], d1);                         \
      d1 = fdot2f(kv[g_].y, qp1[4 * g_ + 1], d1);                         \
      d1 = fdot2f(kv[g_].z, qp1[4 * g_ + 2], d1);                         \
      d1 = fdot2f(kv[g_].w, qp1[4 * g_ + 3], d1);                         \
    }                                                                     \
  }

// load a query pair's packed-f16 row into uniform uints (SGPRs)
#define LOAD_QPAIR(BUF)                                                   \
  {                                                                       \
    const uint4* __restrict__ qb = (const uint4*)(BUF) + (size_t)h * 4 * N_TOK; \
    _Pragma("unroll") for (int gg = 0; gg < 4; gg++) {                    \
      const uint4 a0 = qb[gg * N_TOK + i0];                               \
      const uint4 a1 = qb[gg * N_TOK + i1];                               \
      qp0[4 * gg + 0] = rflu(a0.x); qp0[4 * gg + 1] = rflu(a0.y);         \
      qp0[4 * gg + 2] = rflu(a0.z); qp0[4 * gg + 3] = rflu(a0.w);         \
      qp1[4 * gg + 0] = rflu(a1.x); qp1[4 * gg + 1] = rflu(a1.y);         \
      qp1[4 * gg + 2] = rflu(a1.z); qp1[4 * gg + 3] = rflu(a1.w);         \
    }                                                                     \
  }

// ---------------------------------------------------------------------------
// Kernel 1: QKV projection + l2norm. Normalized streams now written as
// packed f16 planes [h][gg=d/8][n][8]; v_rm stays fp32 row-major.
// grid = (500, 2), block = 256
// ---------------------------------------------------------------------------
__global__ __launch_bounds__(256) void qkv_norm_kernel(
    const float* __restrict__ x_cls, const float* __restrict__ x_reg,
    const float* __restrict__ W_cls, const float* __restrict__ W_reg,
    _Float16* __restrict__ qc_h, _Float16* __restrict__ qr_h,
    _Float16* __restrict__ kc_h, _Float16* __restrict__ kr_h,
    _Float16* __restrict__ vn_h, float* __restrict__ v_rm) {
  __shared__ float xs[4][256];
  __shared__ float res[4][768];
  __shared__ float inv_norm[96];

  const int n0 = blockIdx.x * 4;
  const int which = blockIdx.y;
  const int tid = threadIdx.x;
  const float* __restrict__ x = which ? x_reg : x_cls;
  const float* __restrict__ W = which ? W_reg : W_cls;

#pragma unroll
  for (int r = 0; r < 4; r++) xs[r][tid] = x[(n0 + r) * 256 + tid];
  __syncthreads();

  float acc[4][3];
#pragma unroll
  for (int r = 0; r < 4; r++) acc[r][0] = acc[r][1] = acc[r][2] = 0.f;

  for (int k = 0; k < 256; k++) {
    const float* __restrict__ wr = W + k * 768;
    const float w0 = wr[tid], w1 = wr[tid + 256], w2 = wr[tid + 512];
#pragma unroll
    for (int r = 0; r < 4; r++) {
      const float xv = xs[r][k];
      acc[r][0] += xv * w0;
      acc[r][1] += xv * w1;
      acc[r][2] += xv * w2;
    }
  }
#pragma unroll
  for (int r = 0; r < 4; r++) {
    res[r][tid] = acc[r][0];
    res[r][tid + 256] = acc[r][1];
    res[r][tid + 512] = acc[r][2];
  }
  __syncthreads();

  if (tid < 96) {
    const int r = tid / 24, grp = tid % 24;
    float ss = 0.f;
#pragma unroll
    for (int d = 0; d < HD; d++) {
      const float v = res[r][grp * 32 + d];
      ss += v * v;
    }
    inv_norm[tid] = 1.0f / (sqrtf(ss) + EPSF);
  }
  __syncthreads();

#pragma unroll
  for (int j = 0; j < 3; j++) {
    const int c = tid + j * 256;
    const int qkv = c >> 8, grp = c >> 5;
    const int h = grp & 7, d = c & 31;
    const int gg = d >> 3, dd = d & 7;
#pragma unroll
    for (int r = 0; r < 4; r++) {
      const int n = n0 + r;
      const float val = res[r][c];
      const float nval = val * inv_norm[r * 24 + grp];
      const size_t fi = ((size_t)(h * 4 + gg) * N_TOK + n) * 8 + dd;
      if (qkv == 0) {
        (which ? qr_h : qc_h)[fi] = (_Float16)nval;
      } else if (qkv == 1) {
        (which ? kr_h : kc_h)[fi] = (_Float16)nval;
      } else if (which == 0) {
        v_rm[(h * N_TOK + n) * HD + d] = val;
        vn_h[fi] = (_Float16)nval;
      }
    }
  }
}

// ---------------------------------------------------------------------------
// Kernel 2: round-9 structure (2 queries/block, fixed-shift softmax, sim/raw
// register slots, s_er/part4 LDS union, head rotation, per-phase reduction
// fences) with all score/raw streams in packed f16 + v_dot2_f32_f16 dots:
// half the load traffic, half the dot VALU ops, kv regs 32->16.
// grid = 1000, block = 256
// ---------------------------------------------------------------------------
__global__ __launch_bounds__(256) void attn10_kernel(
    const _Float16* __restrict__ qc_h, const _Float16* __restrict__ qr_h,
    const _Float16* __restrict__ kc_h, const _Float16* __restrict__ kr_h,
    const _Float16* __restrict__ vn_h, const float* __restrict__ v_rm,
    float* __restrict__ out_x, float* __restrict__ out_sim) {
  __shared__ float s_attn[2 * N_TOK];
  __shared__ float s_union[2 * N_TOK];  // er (C/R->combine) / part4 (PV)
  __shared__ float red[4];

  float* __restrict__ s_er = s_union;
  float4* __restrict__ part4 = (float4*)s_union;

  const int tid = threadIdx.x;
  const int i0 = blockIdx.x * 2;
  const int i1 = i0 + 1;
  const int bs = (i0 / 10) * 10;  // i0 even -> i0,i1 share the same decade

  float sim0[NSLOT], sim1[NSLOT], raw0[NSLOT], raw1[NSLOT];
#pragma unroll
  for (int t = 0; t < NSLOT; t++) {
    sim0[t] = 0.f; sim1[t] = 0.f; raw0[t] = 0.f; raw1[t] = 0.f;
  }

  unsigned qp0[16], qp1[16];  // packed f16 query pairs, wave-uniform -> SGPR

  for (int hh = 0; hh < NH; hh++) {
    const int h = (blockIdx.x + hh) & 7;  // XCD-local head schedule

    // ===== phase C: cls scores -> e = exp(s-25) -> s_attn (unnormalized) ===
    LOAD_QPAIR(qc_h);
    float ls0 = 0.f, ls1 = 0.f;
    {
      const uint4* __restrict__ kt4 = (const uint4*)kc_h + (size_t)h * 4 * N_TOK;
#pragma unroll
      for (int t = 0; t < NSLOT; t++) {
        const int m = tid + 256 * t;
        const bool valid = (t < 7) || (tid < NTAIL);
        const int mc = valid ? m : (N_TOK - 1);
        float d0 = 0.f, d1 = 0.f;
        DOT_F16(kt4, mc, d0, d1);
        const float e0 = valid ? __expf(d0 * SCALE - SCALE) : 0.f;
        const float e1 = valid ? __expf(d1 * SCALE - SCALE) : 0.f;
        ls0 += e0; ls1 += e1;
        if (valid) {
          s_attn[m] = e0;
          s_attn[N_TOK + m] = e1;
        }
      }
    }
    const float S0c = block_sum256(ls0, red);
    const float S1c = block_sum256(ls1, red);
    const float n0c = 0.5f / S0c, n1c = 0.5f / S1c;

    // ===== phase R: reg scores -> s_er (own slots only) =====
    LOAD_QPAIR(qr_h);
    float lr0 = 0.f, lr1 = 0.f;
    {
      const uint4* __restrict__ kt4 = (const uint4*)kr_h + (size_t)h * 4 * N_TOK;
#pragma unroll
      for (int t = 0; t < NSLOT; t++) {
        const int m = tid + 256 * t;
        const bool valid = (t < 7) || (tid < NTAIL);
        const int mc = valid ? m : (N_TOK - 1);
        float d0 = 0.f, d1 = 0.f;
        DOT_F16(kt4, mc, d0, d1);
        const float e0 = valid ? __expf(d0 * SCALE - SCALE) : 0.f;
        const float e1 = valid ? __expf(d1 * SCALE - SCALE) : 0.f;
        lr0 += e0; lr1 += e1;
        if (valid) {
          s_er[m] = e0;
          s_er[N_TOK + m] = e1;
        }
      }
    }
    const float S0r = block_sum256(lr0, red);
    const float S1r = block_sum256(lr1, red);
    const float n0r = 0.5f / S0r, n1r = 0.5f / S1r;

    // ===== combine, mask, sim += =====
#pragma unroll
    for (int t = 0; t < NSLOT; t++) {
      const int m = tid + 256 * t;
      if ((t < 7) || (tid < NTAIL)) {
        float a0 = s_attn[m] * n0c + s_er[m] * n0r;
        float a1 = s_attn[N_TOK + m] * n1c + s_er[N_TOK + m] * n1r;
        if (m >= bs && m < bs + 9) {
          if (m != i0) a0 = 0.f;
          if (m != i1) a1 = 0.f;
        }
        s_attn[m] = a0;
        s_attn[N_TOK + m] = a1;
        sim0[t] += a0;
        sim1[t] += a1;
      }
    }

    // ===== phase V: vn cosine -> raw += =====
    LOAD_QPAIR(vn_h);
    {
      const uint4* __restrict__ kt4 = (const uint4*)vn_h + (size_t)h * 4 * N_TOK;
#pragma unroll
      for (int t = 0; t < NSLOT; t++) {
        const int m = tid + 256 * t;
        const bool valid = (t < 7) || (tid < NTAIL);
        const int mc = valid ? m : (N_TOK - 1);
        float d0 = 0.f, d1 = 0.f;
        DOT_F16(kt4, mc, d0, d1);
        if (valid) { raw0[t] += d0; raw1[t] += d1; }
      }
    }
    __syncthreads();  // s_attn final; s_er reads done -> part4 may reuse

    // ===== attn @ V (fp32; part4 overlays s_er storage) =====
    {
      const int g2 = tid & 7, slice = tid >> 3;
      const int m0 = slice * 63;
      const int mend = (m0 + 63 < N_TOK) ? (m0 + 63) : N_TOK;
      float4 a0acc = {0.f, 0.f, 0.f, 0.f}, a1acc = {0.f, 0.f, 0.f, 0.f};
      const float4* __restrict__ v4 = (const float4*)v_rm + (size_t)h * N_TOK * 8;
      for (int m = m0; m < mend; m++) {
        const float4 vv = v4[m * 8 + g2];
        const float a0 = s_attn[m];
        const float a1 = s_attn[N_TOK + m];
        a0acc.x += a0 * vv.x; a0acc.y += a0 * vv.y;
        a0acc.z += a0 * vv.z; a0acc.w += a0 * vv.w;
        a1acc.x += a1 * vv.x; a1acc.y += a1 * vv.y;
        a1acc.z += a1 * vv.z; a1acc.w += a1 * vv.w;
      }
      part4[(slice * 2 + 0) * 8 + g2] = a0acc;
      part4[(slice * 2 + 1) * 8 + g2] = a1acc;
    }
    __syncthreads();
    if (tid < 16) {
      const int q = tid >> 3, g = tid & 7;
      float4 s = {0.f, 0.f, 0.f, 0.f};
#pragma unroll 8
      for (int sl = 0; sl < 32; sl++) {
        const float4 p = part4[(sl * 2 + q) * 8 + g];
        s.x += p.x; s.y += p.y; s.z += p.z; s.w += p.w;
      }
      const int irow = q ? i1 : i0;
      *(float4*)(out_x + (size_t)irow * 512 + h * 32 + 4 * g) = s;
    } else if (tid >= 64 && tid < 128) {
      const int q = (tid - 64) >> 5, d = (tid - 64) & 31;
      const int irow = q ? i1 : i0;
      out_x[(size_t)irow * 512 + 256 + h * 32 + d] =
          v_rm[((size_t)h * N_TOK + irow) * HD + d];
    }
    __syncthreads();  // part4 reads done -> s_er reuse next head
  }

  // ===== sim_round2 epilogue, from registers =====
#pragma unroll
  for (int q = 0; q < 2; q++) {
    const int irow = q ? i1 : i0;
    float* __restrict__ sim = q ? sim1 : sim0;
    float* __restrict__ raw = q ? raw1 : raw0;

    float lm = -1e30f;
#pragma unroll
    for (int t = 0; t < NSLOT; t++) {
      if ((t < 7) || (tid < NTAIL)) lm = fmaxf(lm, sim[t] * 0.125f);
    }
    const float M = block_max256(lm, red);

    float ls = 0.f;
#pragma unroll
    for (int t = 0; t < NSLOT; t++) {
      const bool valid = (t < 7) || (tid < NTAIL);
      const float e = valid ? __expf(sim[t] * 0.125f - M) : 0.f;
      sim[t] = e;
      ls += e;
    }
    const float S = block_sum256(ls, red);
    const float invS = 1.0f / S;

    float lms = 0.f;
#pragma unroll
    for (int t = 0; t < NSLOT; t++) {
      const bool valid = (t < 7) || (tid < NTAIL);
      const float p = sim[t] * invS;
      const float mp = (valid && (raw[t] * 0.125f > SIM_TH)) ? p : 0.f;
      sim[t] = mp;
      lms += mp;
    }
    const float MS = block_sum256(lms, red);
    const float invMS = 1.0f / (MS + EPSF);

#pragma unroll
    for (int t = 0; t < NSLOT; t++) {
      const int m = tid + 256 * t;
      if ((t < 7) || (tid < NTAIL)) {
        out_sim[(size_t)irow * N_TOK + m] = sim[t] * invMS;
      }
    }
  }
}

// ---------------------------------------------------------------------------
extern "C" void kernel_launch(void* const* d_in, const int* in_sizes, int n_in,
                              void* d_out, int out_size, void* d_ws,
                              size_t ws_size, hipStream_t stream) {
  const float* x_cls = (const float*)d_in[0];
  const float* x_reg = (const float*)d_in[1];
  const float* W_cls = (const float*)d_in[2];
  const float* W_reg = (const float*)d_in[3];

  // ws layout: v_rm fp32 [8][2000][32] then five f16 plane buffers
  const size_t seg = (size_t)NH * N_TOK * HD;  // 512000 elements
  float* v_rm = (float*)d_ws;
  _Float16* qc_h = (_Float16*)(v_rm + seg);
  _Float16* qr_h = qc_h + seg;
  _Float16* kc_h = qr_h + seg;
  _Float16* kr_h = kc_h + seg;
  _Float16* vn_h = kr_h + seg;

  dim3 g1(500, 2);
  qkv_norm_kernel<<<g1, 256, 0, stream>>>(x_cls, x_reg, W_cls, W_reg, qc_h,
                                          qr_h, kc_h, kr_h, vn_h, v_rm);

  float* out_x = (float*)d_out;                  // [2000, 512]
  float* out_sim = out_x + (size_t)N_TOK * 512;  // [2000, 2000]
  attn10_kernel<<<1000, 256, 0, stream>>>(qc_h, qr_h, kc_h, kr_h, vn_h, v_rm,
                                          out_x, out_sim);
}

// Round 11
// 343.696 us; speedup vs baseline: 5.2572x; 1.6149x over previous
//
#include <hip/hip_runtime.h>
#include <math.h>

#define N_TOK 2000
#define NH 8
#define HD 32
#define SCALE 25.0f
#define SIM_TH 0.75f
#define EPSF 1e-8f
#define NSLOT 8   // ceil(2000/256)
#define NTAIL 208 // valid lanes in slot 7: 2000 - 7*256
#define SPAD 2048 // padded s_attn stride (PV reads aligned float4)

typedef _Float16 half2_t __attribute__((ext_vector_type(2)));

__device__ __forceinline__ unsigned rflu(unsigned u) {
  return (unsigned)__builtin_amdgcn_readfirstlane((int)u);
}
__device__ __forceinline__ half2_t u2h(unsigned u) {
  return __builtin_bit_cast(half2_t, u);
}

// f32 += f16x2 . f16x2 (v_dot2_f32_f16; products exact, fp32 accumulate)
__device__ __forceinline__ float fdot2f(unsigned a, unsigned b, float c) {
#if __has_builtin(__builtin_amdgcn_fdot2)
  return __builtin_amdgcn_fdot2(u2h(a), u2h(b), c, false);
#else
  const half2_t ha = u2h(a), hb = u2h(b);
  return c + (float)ha.x * (float)hb.x + (float)ha.y * (float)hb.y;
#endif
}

__device__ __forceinline__ float block_max256(float v, float* red) {
#pragma unroll
  for (int off = 32; off > 0; off >>= 1) v = fmaxf(v, __shfl_xor(v, off, 64));
  __syncthreads();
  if ((threadIdx.x & 63) == 0) red[threadIdx.x >> 6] = v;
  __syncthreads();
  return fmaxf(fmaxf(red[0], red[1]), fmaxf(red[2], red[3]));
}
__device__ __forceinline__ float block_sum256(float v, float* red) {
#pragma unroll
  for (int off = 32; off > 0; off >>= 1) v += __shfl_xor(v, off, 64);
  __syncthreads();
  if ((threadIdx.x & 63) == 0) red[threadIdx.x >> 6] = v;
  __syncthreads();
  return (red[0] + red[1]) + (red[2] + red[3]);
}

// load a query pair's packed-f16 row into uniform uints (SGPRs)
#define LOAD_QPAIR(BUF)                                                   \
  {                                                                       \
    const uint4* __restrict__ qb = (const uint4*)(BUF) + (size_t)h * 4 * N_TOK; \
    _Pragma("unroll") for (int gg = 0; gg < 4; gg++) {                    \
      const uint4 a0 = qb[gg * N_TOK + i0];                               \
      const uint4 a1 = qb[gg * N_TOK + i1];                               \
      qp0[4 * gg + 0] = rflu(a0.x); qp0[4 * gg + 1] = rflu(a0.y);         \
      qp0[4 * gg + 2] = rflu(a0.z); qp0[4 * gg + 3] = rflu(a0.w);         \
      qp1[4 * gg + 0] = rflu(a1.x); qp1[4 * gg + 1] = rflu(a1.y);         \
      qp1[4 * gg + 2] = rflu(a1.z); qp1[4 * gg + 3] = rflu(a1.w);         \
    }                                                                     \
  }

// ---------------------------------------------------------------------------
// Kernel 1: QKV projection + l2norm; f16 normalized planes + fp32 v_rm.
// grid = (500, 2), block = 256
// ---------------------------------------------------------------------------
__global__ __launch_bounds__(256) void qkv_norm_kernel(
    const float* __restrict__ x_cls, const float* __restrict__ x_reg,
    const float* __restrict__ W_cls, const float* __restrict__ W_reg,
    _Float16* __restrict__ qc_h, _Float16* __restrict__ qr_h,
    _Float16* __restrict__ kc_h, _Float16* __restrict__ kr_h,
    _Float16* __restrict__ vn_h, float* __restrict__ v_rm) {
  __shared__ float xs[4][256];
  __shared__ float res[4][768];
  __shared__ float inv_norm[96];

  const int n0 = blockIdx.x * 4;
  const int which = blockIdx.y;
  const int tid = threadIdx.x;
  const float* __restrict__ x = which ? x_reg : x_cls;
  const float* __restrict__ W = which ? W_reg : W_cls;

#pragma unroll
  for (int r = 0; r < 4; r++) xs[r][tid] = x[(n0 + r) * 256 + tid];
  __syncthreads();

  float acc[4][3];
#pragma unroll
  for (int r = 0; r < 4; r++) acc[r][0] = acc[r][1] = acc[r][2] = 0.f;

  for (int k = 0; k < 256; k++) {
    const float* __restrict__ wr = W + k * 768;
    const float w0 = wr[tid], w1 = wr[tid + 256], w2 = wr[tid + 512];
#pragma unroll
    for (int r = 0; r < 4; r++) {
      const float xv = xs[r][k];
      acc[r][0] += xv * w0;
      acc[r][1] += xv * w1;
      acc[r][2] += xv * w2;
    }
  }
#pragma unroll
  for (int r = 0; r < 4; r++) {
    res[r][tid] = acc[r][0];
    res[r][tid + 256] = acc[r][1];
    res[r][tid + 512] = acc[r][2];
  }
  __syncthreads();

  if (tid < 96) {
    const int r = tid / 24, grp = tid % 24;
    float ss = 0.f;
#pragma unroll
    for (int d = 0; d < HD; d++) {
      const float v = res[r][grp * 32 + d];
      ss += v * v;
    }
    inv_norm[tid] = 1.0f / (sqrtf(ss) + EPSF);
  }
  __syncthreads();

#pragma unroll
  for (int j = 0; j < 3; j++) {
    const int c = tid + j * 256;
    const int qkv = c >> 8, grp = c >> 5;
    const int h = grp & 7, d = c & 31;
    const int gg = d >> 3, dd = d & 7;
#pragma unroll
    for (int r = 0; r < 4; r++) {
      const int n = n0 + r;
      const float val = res[r][c];
      const float nval = val * inv_norm[r * 24 + grp];
      const size_t fi = ((size_t)(h * 4 + gg) * N_TOK + n) * 8 + dd;
      if (qkv == 0) {
        (which ? qr_h : qc_h)[fi] = (_Float16)nval;
      } else if (qkv == 1) {
        (which ? kr_h : kc_h)[fi] = (_Float16)nval;
      } else if (which == 0) {
        v_rm[(h * N_TOK + n) * HD + d] = val;
        vn_h[fi] = (_Float16)nval;
      }
    }
  }
}

// ---------------------------------------------------------------------------
// Kernel 2: round-10 structure + software-pipelined score sweeps (double-
// buffered kv batches: next batch's 4 loads in flight during current batch's
// 32 fdot2) and batch-4 PV (padded s_attn stride 2048, 2 ds_read_b128 +
// 4 independent v4 loads per batch). Attacks latency exposure only.
// grid = 1000, block = 256
// ---------------------------------------------------------------------------
__global__ __launch_bounds__(256) void attn11_kernel(
    const _Float16* __restrict__ qc_h, const _Float16* __restrict__ qr_h,
    const _Float16* __restrict__ kc_h, const _Float16* __restrict__ kr_h,
    const _Float16* __restrict__ vn_h, const float* __restrict__ v_rm,
    float* __restrict__ out_x, float* __restrict__ out_sim) {
  __shared__ float s_attn[2][SPAD];     // padded; tail stays 0 for PV
  __shared__ float s_union[2 * N_TOK];  // er (C/R->combine) / part4 (PV)
  __shared__ float red[4];

  float* __restrict__ s_er = s_union;
  float4* __restrict__ part4 = (float4*)s_union;

  const int tid = threadIdx.x;
  const int i0 = blockIdx.x * 2;
  const int i1 = i0 + 1;
  const int bs = (i0 / 10) * 10;  // i0 even -> i0,i1 share the same decade

  float sim0[NSLOT], sim1[NSLOT], raw0[NSLOT], raw1[NSLOT];
#pragma unroll
  for (int t = 0; t < NSLOT; t++) {
    sim0[t] = 0.f; sim1[t] = 0.f; raw0[t] = 0.f; raw1[t] = 0.f;
  }
  // zero the PV padding tail once (never rewritten: combine writes m<2000)
  if (tid < SPAD - N_TOK) {
    s_attn[0][N_TOK + tid] = 0.f;
    s_attn[1][N_TOK + tid] = 0.f;
  }
  __syncthreads();

  unsigned qp0[16], qp1[16];  // packed f16 query pairs, wave-uniform -> SGPR

  // pipelined sweep over the 8 m-slots of one f16 K plane: emit(t,d0,d1)
  auto sweep = [&](const uint4* __restrict__ kt4, auto&& emit) {
    uint4 ka[4], kb[4];
#pragma unroll
    for (int g_ = 0; g_ < 4; g_++) ka[g_] = kt4[g_ * N_TOK + tid];  // t=0
#pragma unroll
    for (int t = 0; t < NSLOT; t++) {
      if (t < NSLOT - 1) {  // prefetch t+1 while computing t
        const int m1 = tid + 256 * (t + 1);
        const bool v1 = (t + 1 < 7) || (tid < NTAIL);
        const int mc1 = v1 ? m1 : (N_TOK - 1);
#pragma unroll
        for (int g_ = 0; g_ < 4; g_++) kb[g_] = kt4[g_ * N_TOK + mc1];
      }
      float d0 = 0.f, d1 = 0.f;
#pragma unroll
      for (int g_ = 0; g_ < 4; g_++) {
        d0 = fdot2f(ka[g_].x, qp0[4 * g_ + 0], d0);
        d0 = fdot2f(ka[g_].y, qp0[4 * g_ + 1], d0);
        d0 = fdot2f(ka[g_].z, qp0[4 * g_ + 2], d0);
        d0 = fdot2f(ka[g_].w, qp0[4 * g_ + 3], d0);
        d1 = fdot2f(ka[g_].x, qp1[4 * g_ + 0], d1);
        d1 = fdot2f(ka[g_].y, qp1[4 * g_ + 1], d1);
        d1 = fdot2f(ka[g_].z, qp1[4 * g_ + 2], d1);
        d1 = fdot2f(ka[g_].w, qp1[4 * g_ + 3], d1);
      }
      emit(t, d0, d1);
#pragma unroll
      for (int g_ = 0; g_ < 4; g_++) ka[g_] = kb[g_];
    }
  };

  for (int hh = 0; hh < NH; hh++) {
    const int h = (blockIdx.x + hh) & 7;  // XCD-local head schedule

    // ===== phase C: cls scores -> e = exp(s-25) -> s_attn + running sum ===
    LOAD_QPAIR(qc_h);
    float ls0 = 0.f, ls1 = 0.f;
    sweep((const uint4*)kc_h + (size_t)h * 4 * N_TOK,
          [&](int t, float d0, float d1) {
            const int m = tid + 256 * t;
            const bool valid = (t < 7) || (tid < NTAIL);
            const float e0 = valid ? __expf(d0 * SCALE - SCALE) : 0.f;
            const float e1 = valid ? __expf(d1 * SCALE - SCALE) : 0.f;
            ls0 += e0; ls1 += e1;
            if (valid) {
              s_attn[0][m] = e0;
              s_attn[1][m] = e1;
            }
          });
    const float S0c = block_sum256(ls0, red);
    const float S1c = block_sum256(ls1, red);
    const float n0c = 0.5f / S0c, n1c = 0.5f / S1c;

    // ===== phase R: reg scores -> s_er (own slots only) =====
    LOAD_QPAIR(qr_h);
    float lr0 = 0.f, lr1 = 0.f;
    sweep((const uint4*)kr_h + (size_t)h * 4 * N_TOK,
          [&](int t, float d0, float d1) {
            const int m = tid + 256 * t;
            const bool valid = (t < 7) || (tid < NTAIL);
            const float e0 = valid ? __expf(d0 * SCALE - SCALE) : 0.f;
            const float e1 = valid ? __expf(d1 * SCALE - SCALE) : 0.f;
            lr0 += e0; lr1 += e1;
            if (valid) {
              s_er[m] = e0;
              s_er[N_TOK + m] = e1;
            }
          });
    const float S0r = block_sum256(lr0, red);
    const float S1r = block_sum256(lr1, red);
    const float n0r = 0.5f / S0r, n1r = 0.5f / S1r;

    // ===== combine, mask, sim += =====
#pragma unroll
    for (int t = 0; t < NSLOT; t++) {
      const int m = tid + 256 * t;
      if ((t < 7) || (tid < NTAIL)) {
        float a0 = s_attn[0][m] * n0c + s_er[m] * n0r;
        float a1 = s_attn[1][m] * n1c + s_er[N_TOK + m] * n1r;
        if (m >= bs && m < bs + 9) {
          if (m != i0) a0 = 0.f;
          if (m != i1) a1 = 0.f;
        }
        s_attn[0][m] = a0;
        s_attn[1][m] = a1;
        sim0[t] += a0;
        sim1[t] += a1;
      }
    }

    // ===== phase V: vn cosine -> raw += =====
    LOAD_QPAIR(vn_h);
    sweep((const uint4*)vn_h + (size_t)h * 4 * N_TOK,
          [&](int t, float d0, float d1) {
            const bool valid = (t < 7) || (tid < NTAIL);
            if (valid) { raw0[t] += d0; raw1[t] += d1; }
          });
    __syncthreads();  // s_attn final; s_er reads done -> part4 may reuse

    // ===== attn @ V : 32 slices x 64 m, batch-4 loads (padded tail a=0) ===
    {
      const int g2 = tid & 7, slice = tid >> 3;
      const int m0 = slice * 64;
      float4 a0acc = {0.f, 0.f, 0.f, 0.f}, a1acc = {0.f, 0.f, 0.f, 0.f};
      const float4* __restrict__ v4 = (const float4*)v_rm + (size_t)h * N_TOK * 8;
#pragma unroll 4
      for (int mb = 0; mb < 64; mb += 4) {
        const int m = m0 + mb;
        const float4 av0 = *(const float4*)&s_attn[0][m];
        const float4 av1 = *(const float4*)&s_attn[1][m];
        // pad rows (m>=2000) have a==0; OOB v4 reads stay inside d_ws and
        // are multiplied by 0.
        const float4 vv0 = v4[(size_t)(m + 0) * 8 + g2];
        const float4 vv1 = v4[(size_t)(m + 1) * 8 + g2];
        const float4 vv2 = v4[(size_t)(m + 2) * 8 + g2];
        const float4 vv3 = v4[(size_t)(m + 3) * 8 + g2];
        a0acc.x += av0.x * vv0.x; a0acc.y += av0.x * vv0.y;
        a0acc.z += av0.x * vv0.z; a0acc.w += av0.x * vv0.w;
        a1acc.x += av1.x * vv0.x; a1acc.y += av1.x * vv0.y;
        a1acc.z += av1.x * vv0.z; a1acc.w += av1.x * vv0.w;
        a0acc.x += av0.y * vv1.x; a0acc.y += av0.y * vv1.y;
        a0acc.z += av0.y * vv1.z; a0acc.w += av0.y * vv1.w;
        a1acc.x += av1.y * vv1.x; a1acc.y += av1.y * vv1.y;
        a1acc.z += av1.y * vv1.z; a1acc.w += av1.y * vv1.w;
        a0acc.x += av0.z * vv2.x; a0acc.y += av0.z * vv2.y;
        a0acc.z += av0.z * vv2.z; a0acc.w += av0.z * vv2.w;
        a1acc.x += av1.z * vv2.x; a1acc.y += av1.z * vv2.y;
        a1acc.z += av1.z * vv2.z; a1acc.w += av1.z * vv2.w;
        a0acc.x += av0.w * vv3.x; a0acc.y += av0.w * vv3.y;
        a0acc.z += av0.w * vv3.z; a0acc.w += av0.w * vv3.w;
        a1acc.x += av1.w * vv3.x; a1acc.y += av1.w * vv3.y;
        a1acc.z += av1.w * vv3.z; a1acc.w += av1.w * vv3.w;
      }
      __syncthreads();  // s_er reads in combine long done; part4 write safe
      part4[(slice * 2 + 0) * 8 + g2] = a0acc;
      part4[(slice * 2 + 1) * 8 + g2] = a1acc;
    }
    __syncthreads();
    if (tid < 16) {
      const int q = tid >> 3, g = tid & 7;
      float4 s = {0.f, 0.f, 0.f, 0.f};
#pragma unroll 8
      for (int sl = 0; sl < 32; sl++) {
        const float4 p = part4[(sl * 2 + q) * 8 + g];
        s.x += p.x; s.y += p.y; s.z += p.z; s.w += p.w;
      }
      const int irow = q ? i1 : i0;
      *(float4*)(out_x + (size_t)irow * 512 + h * 32 + 4 * g) = s;
    } else if (tid >= 64 && tid < 128) {
      const int q = (tid - 64) >> 5, d = (tid - 64) & 31;
      const int irow = q ? i1 : i0;
      out_x[(size_t)irow * 512 + 256 + h * 32 + d] =
          v_rm[((size_t)h * N_TOK + irow) * HD + d];
    }
    __syncthreads();  // part4 reads done -> s_er reuse next head
  }

  // ===== sim_round2 epilogue, from registers =====
#pragma unroll
  for (int q = 0; q < 2; q++) {
    const int irow = q ? i1 : i0;
    float* __restrict__ sim = q ? sim1 : sim0;
    float* __restrict__ raw = q ? raw1 : raw0;

    float lm = -1e30f;
#pragma unroll
    for (int t = 0; t < NSLOT; t++) {
      if ((t < 7) || (tid < NTAIL)) lm = fmaxf(lm, sim[t] * 0.125f);
    }
    const float M = block_max256(lm, red);

    float ls = 0.f;
#pragma unroll
    for (int t = 0; t < NSLOT; t++) {
      const bool valid = (t < 7) || (tid < NTAIL);
      const float e = valid ? __expf(sim[t] * 0.125f - M) : 0.f;
      sim[t] = e;
      ls += e;
    }
    const float S = block_sum256(ls, red);
    const float invS = 1.0f / S;

    float lms = 0.f;
#pragma unroll
    for (int t = 0; t < NSLOT; t++) {
      const bool valid = (t < 7) || (tid < NTAIL);
      const float p = sim[t] * invS;
      const float mp = (valid && (raw[t] * 0.125f > SIM_TH)) ? p : 0.f;
      sim[t] = mp;
      lms += mp;
    }
    const float MS = block_sum256(lms, red);
    const float invMS = 1.0f / (MS + EPSF);

#pragma unroll
    for (int t = 0; t < NSLOT; t++) {
      const int m = tid + 256 * t;
      if ((t < 7) || (tid < NTAIL)) {
        out_sim[(size_t)irow * N_TOK + m] = sim[t] * invMS;
      }
    }
  }
}

// ---------------------------------------------------------------------------
extern "C" void kernel_launch(void* const* d_in, const int* in_sizes, int n_in,
                              void* d_out, int out_size, void* d_ws,
                              size_t ws_size, hipStream_t stream) {
  const float* x_cls = (const float*)d_in[0];
  const float* x_reg = (const float*)d_in[1];
  const float* W_cls = (const float*)d_in[2];
  const float* W_reg = (const float*)d_in[3];

  // ws layout: v_rm fp32 [8][2000][32] then five f16 plane buffers
  const size_t seg = (size_t)NH * N_TOK * HD;  // 512000 elements
  float* v_rm = (float*)d_ws;
  _Float16* qc_h = (_Float16*)(v_rm + seg);
  _Float16* qr_h = qc_h + seg;
  _Float16* kc_h = qr_h + seg;
  _Float16* kr_h = kc_h + seg;
  _Float16* vn_h = kr_h + seg;

  dim3 g1(500, 2);
  qkv_norm_kernel<<<g1, 256, 0, stream>>>(x_cls, x_reg, W_cls, W_reg, qc_h,
                                          qr_h, kc_h, kr_h, vn_h, v_rm);

  float* out_x = (float*)d_out;                  // [2000, 512]
  float* out_sim = out_x + (size_t)N_TOK * 512;  // [2000, 2000]
  attn11_kernel<<<1000, 256, 0, stream>>>(qc_h, qr_h, kc_h, kr_h, vn_h, v_rm,
                                          out_x, out_sim);
}